// Round 1
// 515.802 us; speedup vs baseline: 1.0279x; 1.0279x over previous
//
#include <hip/hip_runtime.h>
#include <hip/hip_bf16.h>

#define NUSERS 200000
#define NITEMS 100000
#define NNODES 300000
#define EDIM   64
#define NEDGES 2000000
#define SCAN_NB ((NNODES + 255) / 256)   // 1172 blocks
#define FILL_BLOCKS 2048
#define NPASS 4
#define EB4 ((NEDGES / 4 + 255) / 256)   // 1954 hist blocks
#define CB  ((NNODES * 16 + 255) / 256)  // 18750 convert blocks
#define SPMM_BLOCKS 2048                 // 8 blocks/CU persistent
#define SPMM_STRIDE (SPMM_BLOCKS * 4)    // waves per sweep

typedef unsigned short u16;

__device__ __forceinline__ float bf2f(u16 h) {
    return __uint_as_float((unsigned)h << 16);
}
__device__ __forceinline__ u16 f2bf(float f) {
    union { __hip_bfloat16 b; u16 u; } c;
    c.b = __float2bfloat16(f);   // RNE
    return c.u;
}

// ---------------- fused histogram + bf16 convert ----------------
// hist (atomic-latency-bound) and convert (stream-BW-bound) are independent
// heads of the DAG: run them in one grid so they overlap.
__global__ void k_prep(const int4* __restrict__ dst4, int* __restrict__ cnt,
                       const float4* __restrict__ uq, const float4* __restrict__ iq,
                       ushort4* __restrict__ xb4) {
    int b = blockIdx.x;
    if (b < EB4) {
        int i = b * 256 + threadIdx.x;
        if (i < NEDGES / 4) {
            int4 d = dst4[i];
            atomicAdd(&cnt[d.x], 1);
            atomicAdd(&cnt[d.y], 1);
            atomicAdd(&cnt[d.z], 1);
            atomicAdd(&cnt[d.w], 1);
        }
    } else {
        int i = (b - EB4) * 256 + threadIdx.x;
        if (i < NNODES * 16) {
            float4 v = (i < NUSERS * 16) ? uq[i] : iq[i - NUSERS * 16];
            ushort4 h;
            h.x = f2bf(v.x); h.y = f2bf(v.y); h.z = f2bf(v.z); h.w = f2bf(v.w);
            xb4[i] = h;
        }
    }
}

// ---------------- scan (unchanged) ----------------

__global__ void k_scan1(int* __restrict__ data, int* __restrict__ bsum) {
    __shared__ int s[256];
    int i = blockIdx.x * 256 + threadIdx.x;
    int v = (i < NNODES) ? data[i] : 0;
    s[threadIdx.x] = v;
    __syncthreads();
    for (int o = 1; o < 256; o <<= 1) {
        int t = (threadIdx.x >= o) ? s[threadIdx.x - o] : 0;
        __syncthreads();
        s[threadIdx.x] += t;
        __syncthreads();
    }
    if (i < NNODES) data[i] = s[threadIdx.x] - v;          // exclusive
    if (threadIdx.x == 255) bsum[blockIdx.x] = s[255];     // inclusive total
}

__global__ void k_scan2(int* __restrict__ bsum) {
    __shared__ int s[256];
    __shared__ int carry;
    if (threadIdx.x == 0) carry = 0;
    __syncthreads();
    for (int base = 0; base < SCAN_NB; base += 256) {
        int i = base + threadIdx.x;
        int v = (i < SCAN_NB) ? bsum[i] : 0;
        s[threadIdx.x] = v;
        __syncthreads();
        for (int o = 1; o < 256; o <<= 1) {
            int t = (threadIdx.x >= o) ? s[threadIdx.x - o] : 0;
            __syncthreads();
            s[threadIdx.x] += t;
            __syncthreads();
        }
        if (i < SCAN_NB) bsum[i] = s[threadIdx.x] - v + carry;
        __syncthreads();
        if (threadIdx.x == 0) carry += s[255];
        __syncthreads();
    }
}

__global__ void k_scan3(int* __restrict__ off, const int* __restrict__ bscan,
                        int* __restrict__ wpos) {
    int i = blockIdx.x * 256 + threadIdx.x;
    if (i < NNODES) {
        int v = off[i] + bscan[blockIdx.x];
        off[i] = v;
        wpos[i] = v;
    }
    if (i == 0) off[NNODES] = NEDGES;   // sentinel: spmm reads off[n+1] unconditionally
}

// ---------------- windowed fill (unchanged) ----------------

__global__ void k_fill_win(const int* __restrict__ src, const int4* __restrict__ dst4,
                           const float* __restrict__ w, int* __restrict__ wpos,
                           int2* __restrict__ edata) {
    const int W = (NNODES + NPASS - 1) / NPASS;
    for (int k = 0; k < NPASS; ++k) {
        int lo = k * W;
        int hi = lo + W;
        for (int i = blockIdx.x * 256 + threadIdx.x; i < NEDGES / 4;
             i += FILL_BLOCKS * 256) {
            int4 d = dst4[i];
            int e = i * 4;
            if (d.x >= lo && d.x < hi) {
                int p = atomicAdd(&wpos[d.x], 1);
                edata[p] = make_int2(src[e], __float_as_int(w[e]));
            }
            if (d.y >= lo && d.y < hi) {
                int p = atomicAdd(&wpos[d.y], 1);
                edata[p] = make_int2(src[e + 1], __float_as_int(w[e + 1]));
            }
            if (d.z >= lo && d.z < hi) {
                int p = atomicAdd(&wpos[d.z], 1);
                edata[p] = make_int2(src[e + 2], __float_as_int(w[e + 2]));
            }
            if (d.w >= lo && d.w < hi) {
                int p = atomicAdd(&wpos[d.w], 1);
                edata[p] = make_int2(src[e + 3], __float_as_int(w[e + 3]));
            }
        }
    }
}

// ---------------- gather SpMM v2 ----------------
// Latency-bound before (VALU 46%, HBM 30%, occ 76%): per-node chain
// off->edata->row (~3x700cy) with 8 edges in flight and 75k short blocks.
// v2: persistent waves (8 blocks/CU), next-node off prefetch, batch-16
// clamped edata loads + exec-masked row gathers (all 4+4 loads issued
// before first use; masked lanes make no memory requests).

__device__ __forceinline__ float4 bfrow(const ushort4* __restrict__ xb4, int s, int l16) {
    // 32-bit byte offset (table < 4 GB): folds into SGPR-base + voffset
    const ushort4* p = (const ushort4*)((const char*)xb4 +
                       (((unsigned)s << 7) + ((unsigned)l16 << 3)));
    ushort4 h = *p;
    float4 v;
    v.x = bf2f(h.x); v.y = bf2f(h.y); v.z = bf2f(h.z); v.w = bf2f(h.w);
    return v;
}

__device__ __forceinline__ int2 ld_edge(const int2* __restrict__ e, int i) {
    return *(const int2*)((const char*)e + ((unsigned)i << 3));
}

__global__ __launch_bounds__(256, 8)
void k_spmm1(const ushort4* __restrict__ xb4, const int* __restrict__ off,
             const int2* __restrict__ edata, ushort4* __restrict__ x1b4) {
    const int wid  = threadIdx.x >> 6;
    const int lane = threadIdx.x & 63;
    const int q    = lane >> 4;          // slot 0..3
    const int l16  = lane & 15;          // 16 lanes x ushort4 = 64 dims
    int n = blockIdx.x * 4 + wid;
    int o0 = off[n];
    int o1 = off[n + 1];
    while (n < NNODES) {
        int nn = n + SPMM_STRIDE;
        int no0 = 0, no1 = 0;
        if (nn < NNODES) { no0 = off[nn]; no1 = off[nn + 1]; }  // prefetch
        int deg = o1 - o0;
        int cap = o1 - 1; if (cap < 0) cap = 0;
        int b0 = o0 + q;
        int p0 = b0;      if (p0 > cap) p0 = cap;
        int p1 = b0 + 4;  if (p1 > cap) p1 = cap;
        int p2 = b0 + 8;  if (p2 > cap) p2 = cap;
        int p3 = b0 + 12; if (p3 > cap) p3 = cap;
        int2 e0 = ld_edge(edata, p0);
        int2 e1 = ld_edge(edata, p1);
        int2 e2 = ld_edge(edata, p2);
        int2 e3 = ld_edge(edata, p3);
        float4 v0 = make_float4(0.f, 0.f, 0.f, 0.f);
        float4 v1 = v0, v2 = v0, v3 = v0;
        if (q < deg)      v0 = bfrow(xb4, e0.x, l16);
        if (q + 4 < deg)  v1 = bfrow(xb4, e1.x, l16);
        if (q + 8 < deg)  v2 = bfrow(xb4, e2.x, l16);
        if (q + 12 < deg) v3 = bfrow(xb4, e3.x, l16);
        float w0 = __int_as_float(e0.y), w1 = __int_as_float(e1.y);
        float w2 = __int_as_float(e2.y), w3 = __int_as_float(e3.y);
        float4 a0, a1;
        a0.x = w0 * v0.x; a0.y = w0 * v0.y; a0.z = w0 * v0.z; a0.w = w0 * v0.w;
        a1.x = w1 * v1.x; a1.y = w1 * v1.y; a1.z = w1 * v1.z; a1.w = w1 * v1.w;
        a0.x += w2 * v2.x; a0.y += w2 * v2.y; a0.z += w2 * v2.z; a0.w += w2 * v2.w;
        a1.x += w3 * v3.x; a1.y += w3 * v3.y; a1.z += w3 * v3.z; a1.w += w3 * v3.w;
        if (deg > 16) {                       // rare tail (P ~ 0.04%)
            for (int p = b0 + 16; p < o1; p += 4) {
                int2 e = ld_edge(edata, p);
                float4 v = bfrow(xb4, e.x, l16);
                float w = __int_as_float(e.y);
                a0.x += w * v.x; a0.y += w * v.y; a0.z += w * v.z; a0.w += w * v.w;
            }
        }
        a0.x += a1.x; a0.y += a1.y; a0.z += a1.z; a0.w += a1.w;
        a0.x += __shfl_xor(a0.x, 16, 64); a0.y += __shfl_xor(a0.y, 16, 64);
        a0.z += __shfl_xor(a0.z, 16, 64); a0.w += __shfl_xor(a0.w, 16, 64);
        a0.x += __shfl_xor(a0.x, 32, 64); a0.y += __shfl_xor(a0.y, 32, 64);
        a0.z += __shfl_xor(a0.z, 32, 64); a0.w += __shfl_xor(a0.w, 32, 64);
        if (q == 0) {
            ushort4 h;
            h.x = f2bf(a0.x); h.y = f2bf(a0.y); h.z = f2bf(a0.z); h.w = f2bf(a0.w);
            x1b4[(size_t)n * 16 + l16] = h;
        }
        n = nn; o0 = no0; o1 = no1;
    }
}

__global__ __launch_bounds__(256, 8)
void k_spmm2(const float4* __restrict__ uq, const float4* __restrict__ iq,
             const ushort4* __restrict__ x1b4, const int* __restrict__ off,
             const int2* __restrict__ edata, float4* __restrict__ outq) {
    const int wid  = threadIdx.x >> 6;
    const int lane = threadIdx.x & 63;
    const int q    = lane >> 4;
    const int l16  = lane & 15;
    int n = blockIdx.x * 4 + wid;
    int o0 = off[n];
    int o1 = off[n + 1];
    while (n < NNODES) {
        int nn = n + SPMM_STRIDE;
        int no0 = 0, no1 = 0;
        if (nn < NNODES) { no0 = off[nn]; no1 = off[nn + 1]; }
        int deg = o1 - o0;
        int cap = o1 - 1; if (cap < 0) cap = 0;
        int b0 = o0 + q;
        int p0 = b0;      if (p0 > cap) p0 = cap;
        int p1 = b0 + 4;  if (p1 > cap) p1 = cap;
        int p2 = b0 + 8;  if (p2 > cap) p2 = cap;
        int p3 = b0 + 12; if (p3 > cap) p3 = cap;
        int2 e0 = ld_edge(edata, p0);
        int2 e1 = ld_edge(edata, p1);
        int2 e2 = ld_edge(edata, p2);
        int2 e3 = ld_edge(edata, p3);
        float4 v0 = make_float4(0.f, 0.f, 0.f, 0.f);
        float4 v1 = v0, v2 = v0, v3 = v0;
        if (q < deg)      v0 = bfrow(x1b4, e0.x, l16);
        if (q + 4 < deg)  v1 = bfrow(x1b4, e1.x, l16);
        if (q + 8 < deg)  v2 = bfrow(x1b4, e2.x, l16);
        if (q + 12 < deg) v3 = bfrow(x1b4, e3.x, l16);
        float w0 = __int_as_float(e0.y), w1 = __int_as_float(e1.y);
        float w2 = __int_as_float(e2.y), w3 = __int_as_float(e3.y);
        float4 a0, a1;
        a0.x = w0 * v0.x; a0.y = w0 * v0.y; a0.z = w0 * v0.z; a0.w = w0 * v0.w;
        a1.x = w1 * v1.x; a1.y = w1 * v1.y; a1.z = w1 * v1.z; a1.w = w1 * v1.w;
        a0.x += w2 * v2.x; a0.y += w2 * v2.y; a0.z += w2 * v2.z; a0.w += w2 * v2.w;
        a1.x += w3 * v3.x; a1.y += w3 * v3.y; a1.z += w3 * v3.z; a1.w += w3 * v3.w;
        if (deg > 16) {
            for (int p = b0 + 16; p < o1; p += 4) {
                int2 e = ld_edge(edata, p);
                float4 v = bfrow(x1b4, e.x, l16);
                float w = __int_as_float(e.y);
                a0.x += w * v.x; a0.y += w * v.y; a0.z += w * v.z; a0.w += w * v.w;
            }
        }
        a0.x += a1.x; a0.y += a1.y; a0.z += a1.z; a0.w += a1.w;
        a0.x += __shfl_xor(a0.x, 16, 64); a0.y += __shfl_xor(a0.y, 16, 64);
        a0.z += __shfl_xor(a0.z, 16, 64); a0.w += __shfl_xor(a0.w, 16, 64);
        a0.x += __shfl_xor(a0.x, 32, 64); a0.y += __shfl_xor(a0.y, 32, 64);
        a0.z += __shfl_xor(a0.z, 32, 64); a0.w += __shfl_xor(a0.w, 32, 64);
        if (q == 0) {
            size_t ridx = (size_t)n * 16 + l16;
            float4 x0 = (n < NUSERS) ? uq[ridx] : iq[ridx - (size_t)NUSERS * 16];
            float4 x1v = bfrow(x1b4, n, l16);
            const float s = 1.0f / 3.0f;
            float4 r;
            r.x = (x0.x + x1v.x + a0.x) * s;
            r.y = (x0.y + x1v.y + a0.y) * s;
            r.z = (x0.z + x1v.z + a0.z) * s;
            r.w = (x0.w + x1v.w + a0.w) * s;
            outq[ridx] = r;
        }
        n = nn; o0 = no0; o1 = no1;
    }
}

// ---------------- fallback (atomic path, if ws too small) ----------------

__global__ void scatter_l1(const float* __restrict__ u, const float* __restrict__ it,
                           float* __restrict__ y,
                           const int* __restrict__ src, const int* __restrict__ dst,
                           const float* __restrict__ w) {
    long long t = (long long)blockIdx.x * blockDim.x + threadIdx.x;
    int e = (int)(t >> 4);
    if (e >= NEDGES) return;
    int q = (int)(t & 15);
    int s = src[e], d = dst[e];
    float we = w[e];
    const float* xrow = (s < NUSERS) ? (u + (size_t)s * EDIM)
                                     : (it + (size_t)(s - NUSERS) * EDIM);
    float4 v = ((const float4*)xrow)[q];
    float* yp = y + (size_t)d * EDIM + q * 4;
    atomicAdd(yp + 0, we * v.x);
    atomicAdd(yp + 1, we * v.y);
    atomicAdd(yp + 2, we * v.z);
    atomicAdd(yp + 3, we * v.w);
}

__global__ void scatter_gen(const float* __restrict__ x, float* __restrict__ y,
                            const int* __restrict__ src, const int* __restrict__ dst,
                            const float* __restrict__ w) {
    long long t = (long long)blockIdx.x * blockDim.x + threadIdx.x;
    int e = (int)(t >> 4);
    if (e >= NEDGES) return;
    int q = (int)(t & 15);
    int s = src[e], d = dst[e];
    float we = w[e];
    float4 v = ((const float4*)(x + (size_t)s * EDIM))[q];
    float* yp = y + (size_t)d * EDIM + q * 4;
    atomicAdd(yp + 0, we * v.x);
    atomicAdd(yp + 1, we * v.y);
    atomicAdd(yp + 2, we * v.z);
    atomicAdd(yp + 3, we * v.w);
}

__global__ void final_kernel(const float4* __restrict__ u, const float4* __restrict__ it,
                             const float4* __restrict__ x2, float4* __restrict__ outq) {
    int i = blockIdx.x * blockDim.x + threadIdx.x;
    const int uq = NUSERS * EDIM / 4;
    const int nq = NNODES * EDIM / 4;
    if (i >= nq) return;
    float4 x0 = (i < uq) ? u[i] : it[i - uq];
    float4 x1 = outq[i];
    float4 a  = x2[i];
    const float s = 1.0f / 3.0f;
    float4 r;
    r.x = (x0.x + x1.x + a.x) * s;
    r.y = (x0.y + x1.y + a.y) * s;
    r.z = (x0.z + x1.z + a.z) * s;
    r.w = (x0.w + x1.w + a.w) * s;
    outq[i] = r;
}

// ---------------- launch ----------------

extern "C" void kernel_launch(void* const* d_in, const int* in_sizes, int n_in,
                              void* d_out, int out_size, void* d_ws, size_t ws_size,
                              hipStream_t stream) {
    const float* u   = (const float*)d_in[0];
    const float* it  = (const float*)d_in[1];
    const int*   src = (const int*)d_in[2];
    const int*   dst = (const int*)d_in[3];
    const float* w   = (const float*)d_in[4];
    float* out = (float*)d_out;

    const size_t nd = (size_t)NNODES * EDIM;

    // ws layout (full path) — off has +8 pad for the off[NNODES] sentinel
    int*     off   = (int*)d_ws;                 // NNODES+8
    int*     wpos  = off + NNODES + 8;           // NNODES
    int*     bscan = wpos + NNODES;              // 2048 (>= SCAN_NB)
    int2*    edata = (int2*)(bscan + 2048);      // NEDGES packed (src, w)
    ushort4* xb4   = (ushort4*)(edata + NEDGES); // NNODES*16 (bf16 x0)
    ushort4* x1b4  = xb4 + (size_t)NNODES * 16;  // NNODES*16 (bf16 x1)
    const size_t needed =
        (size_t)(NNODES + 8 + NNODES + 2048) * sizeof(int) +
        (size_t)NEDGES * sizeof(int2) +
        (size_t)NNODES * 16 * sizeof(ushort4) * 2;

    dim3 blk(256);

    if (ws_size >= needed) {
        // --- CSR counts + bf16 convert (fused, independent DAG heads) ---
        hipMemsetAsync(off, 0, (size_t)NNODES * sizeof(int), stream);
        k_prep <<<EB4 + CB, blk, 0, stream>>>((const int4*)dst, off,
                                              (const float4*)u, (const float4*)it, xb4);
        k_scan1<<<SCAN_NB, blk, 0, stream>>>(off, bscan);
        k_scan2<<<1, blk, 0, stream>>>(bscan);
        k_scan3<<<SCAN_NB, blk, 0, stream>>>(off, bscan, wpos);
        k_fill_win<<<FILL_BLOCKS, blk, 0, stream>>>(src, (const int4*)dst, w, wpos, edata);
        // --- layer 1: x1b = bf16(A @ xb) ---
        k_spmm1<<<SPMM_BLOCKS, blk, 0, stream>>>(xb4, off, edata, x1b4);
        // --- layer 2 + epilogue: out = (x0 + x1 + A@x1)/3 ---
        k_spmm2<<<SPMM_BLOCKS, blk, 0, stream>>>((const float4*)u, (const float4*)it,
                                                 x1b4, off, edata, (float4*)out);
    } else {
        // fallback: atomic scatter path (requires only 76.8 MB ws)
        float* A = (float*)d_ws;
        hipMemsetAsync(out, 0, nd * sizeof(float), stream);
        long long nthreads = (long long)NEDGES * 16;
        int sblocks = (int)((nthreads + 255) / 256);
        scatter_l1<<<sblocks, blk, 0, stream>>>(u, it, out, src, dst, w);
        hipMemsetAsync(A, 0, nd * sizeof(float), stream);
        scatter_gen<<<sblocks, blk, 0, stream>>>(out, A, src, dst, w);
        final_kernel<<<(NNODES * EDIM / 4 + 255) / 256, blk, 0, stream>>>(
            (const float4*)u, (const float4*)it, (const float4*)A, (float4*)out);
    }
}